// Round 10
// baseline (138.714 us; speedup 1.0000x reference)
//
#include <hip/hip_runtime.h>
#include <hip/hip_bf16.h>
#include <stdint.h>

#define SEQ 4096
#define DM  1024

typedef __attribute__((ext_vector_type(8))) short  s16x8;
typedef __attribute__((ext_vector_type(8))) _Float16 h16x8;
typedef __attribute__((ext_vector_type(4))) float  f32x4;

__device__ __forceinline__ ushort f2bf(float f) {
    union { float f; uint32_t u; } x; x.f = f;
    uint32_t r = x.u + 0x7fffu + ((x.u >> 16) & 1u);
    return (ushort)(r >> 16);
}

__device__ __forceinline__ void gload16(const void* g, void* l) {
    __builtin_amdgcn_global_load_lds(
        (const __attribute__((address_space(1))) void*)g,
        (__attribute__((address_space(3))) void*)l,
        16, 0, 0);
}

// inverse of the read-side swizzle T(b) = b ^ (((b>>6)&7)<<4)
// (T bijective, NOT an involution: bit6 feedback). Derived exact inverse.
__device__ __forceinline__ int invswz(int x) {
    const int x6 = (x >> 6) & 1, x7 = (x >> 7) & 1, x8 = (x >> 8) & 1;
    return x ^ (x8 << 6) ^ (x7 << 5) ^ ((x6 ^ x8) << 4);
}

// ---------------------------------------------------------------------------
// fused fp32->bf16 convert of x + wq + wk + wv (one launch)
// ---------------------------------------------------------------------------
__global__ __launch_bounds__(256)
void cvt_all(const float* __restrict__ x,  const float* __restrict__ wq,
             const float* __restrict__ wk, const float* __restrict__ wv,
             ushort* __restrict__ xb,  ushort* __restrict__ wqb,
             ushort* __restrict__ wkb, ushort* __restrict__ wvb)
{
    int i = blockIdx.x * 256 + threadIdx.x;      // grid sized exactly (7168*256)
    const float* src; ushort* dst; int k;
    if (i < 1048576) { src = x; dst = xb; k = i; }
    else {
        int j = i - 1048576; int w = j >> 18; k = j & 262143;
        src = (w == 0) ? wq : (w == 1) ? wk : wv;
        dst = (w == 0) ? wqb : (w == 1) ? wkb : wvb;
    }
    float4 v = ((const float4*)src)[k];
    ushort4 o;
    o.x = f2bf(v.x); o.y = f2bf(v.y); o.z = f2bf(v.z); o.w = f2bf(v.w);
    ((ushort4*)dst)[k] = o;
}

// ===========================================================================
// 8-phase 256-row GEMM template (C = A[M,K] * B[N,K]^T, bf16 in).
// MODE 0: scores — BN=256, LDA=1024, 16 K-tiles, grid 256, f16 out.
// MODE 1: PV split-K=2 — BN=128, LDA=4096, 32 K-tiles/slice, grid 256,
//         f16 partials; merged phases (16 MFMA per barrier).
// MODE 2: fused QKV — BN=256, LDA=1024, grid 192, bf16 out + bias/scale.
// Round-10 changes vs round 9 (stagger/vmcnt algebra UNCHANGED):
//  * ONE barrier per phase: {reads; stage; lgkm0; SGB; MFMA; [vmcnt]; bar}.
//    Region-disjointness verified for every stage-target vs same/next-window
//    readers; every stage-target's last readers are >=1 barrier behind.
//  * New LDS swizzle T(b)=b^(((b>>6)&7)<<4): even 4x bank-slot spread for
//    ds_read_b128 (was 8x on half the slots). Staging uses exact inverse.
// ===========================================================================
template<int MODE>
__global__ __launch_bounds__(512, 1)
void gemm256p(const ushort* __restrict__ pA,  const ushort* __restrict__ pB,  void* __restrict__ pC,
              const ushort* __restrict__ pA2, const ushort* __restrict__ pB2, void* __restrict__ pC2,
              const ushort* __restrict__ pA3, const ushort* __restrict__ pB3, void* __restrict__ pC3,
              const float* __restrict__ pb1,  const float* __restrict__ pb2,  const float* __restrict__ pb3)
{
    constexpr int BN      = (MODE == 1) ? 128 : 256;
    constexpr int WN      = BN / 4;
    constexpr int NJ      = BN / 64;
    constexpr int LDA     = (MODE == 1) ? 4096 : 1024;
    constexpr int REG_A   = 16384;               // A half-tile bytes [256][32]
    constexpr int REG_B   = BN * 64;             // B half-tile bytes [BN][32]
    constexpr int BUFSZ   = 2 * (REG_A + REG_B);
    constexpr int NTILES  = (MODE == 1) ? 32 : 16;
    constexpr int TOTAL_H = NTILES * 4;
    constexpr int NWG     = (MODE == 2) ? 192 : 256;

    __shared__ alignas(16) char lb[2 * BUFSZ];

    const int wg = blockIdx.x;
    const int logical = (wg & 7) * (NWG / 8) + (wg >> 3);

    int m0, n0, ldc_ = 0, biasRow = 0;
    const ushort *Ab, *Bb;
    char* Cc;
    const float* bias = nullptr;
    float scale = 1.0f;

    if constexpr (MODE == 0) {
        const int bx = logical & 15, by = logical >> 4;
        m0 = by * 256; n0 = bx * 256;
        Ab = pA + (size_t)m0 * LDA; Bb = pB + (size_t)n0 * LDA;
        Cc = (char*)pC; ldc_ = 4096;
    } else if constexpr (MODE == 1) {
        const int t = logical >> 1, ks = logical & 1;
        m0 = (t >> 3) * 256; n0 = (t & 7) * 128;
        Ab = pA + (size_t)m0 * LDA + ks * 2048;
        Bb = pB + (size_t)n0 * LDA + ks * 2048;
        Cc = (char*)pC + (size_t)ks * 8388608u;  // 4096*1024 f16 elems
        ldc_ = 1024;
    } else {
        const int which = logical / 64, t = logical % 64;
        if (which == 0)      { m0 = (t >> 2) * 256; n0 = (t & 3) * 256;  Ab = pA;  Bb = pB;  Cc = (char*)pC;  bias = pb1; scale = 0.03125f; ldc_ = 1024; }
        else if (which == 1) { m0 = (t >> 2) * 256; n0 = (t & 3) * 256;  Ab = pA2; Bb = pB2; Cc = (char*)pC2; bias = pb2; ldc_ = 1024; }
        else                 { m0 = (t >> 4) * 256; n0 = (t & 15) * 256; Ab = pA3; Bb = pB3; Cc = (char*)pC3; bias = pb3; biasRow = 1; ldc_ = 4096; }
        Ab += (size_t)m0 * LDA; Bb += (size_t)n0 * LDA;
    }

    const int tid = threadIdx.x;
    const int w = tid >> 6, l = tid & 63;
    const int wr = w >> 2, wc = w & 3;
    const int lm = l & 15;
    const int khb = (l >> 4) * 16;

    // staging decode: LDS linear dst at in0/in1; global source = T^-1(dst)
    const int in0 = tid * 16, in1 = 8192 + tid * 16;
    const int b0 = invswz(in0), b1 = invswz(in1);
    const int r0_ = b0 >> 6, c0_ = (b0 & 63) >> 1;
    const int r1_ = b1 >> 6, c1_ = (b1 & 63) >> 1;

    // ds-read bases with T: base ^ ((row&7)<<4); row&7 == lm&7 for all frags
    const int abase = (wr * 128 + lm) * 64 + khb;
    const int bbase = (wc * WN  + lm) * 64 + khb;
    const int aoff = abase ^ ((lm & 7) << 4);
    const int boff = bbase ^ ((lm & 7) << 4);

    f32x4 acc[8][NJ] = {};
    s16x8 bqr[NJ];

    // region byte offsets within a buffer: A0, B0, A1, B1
    constexpr int AR0 = 0, BR0 = REG_A, AR1 = REG_A + REG_B, BR1 = 2 * REG_A + REG_B;

#define ROFFX(reg_) ((reg_) == 0 ? AR0 : (reg_) == 1 ? BR0 : (reg_) == 2 ? AR1 : BR1)

#define STAGE_H(g) do { \
    const int hidx_ = (g) - 1, tile_ = hidx_ >> 2, reg_ = hidx_ & 3; \
    const int colb_ = tile_ * 64 + (reg_ >> 1) * 32; \
    char* dst_ = lb + (tile_ & 1) * BUFSZ + ROFFX(reg_); \
    if (reg_ & 1) { \
        gload16(Bb + (size_t)r0_ * LDA + colb_ + c0_, dst_ + in0); \
        if (BN == 256) gload16(Bb + (size_t)r1_ * LDA + colb_ + c1_, dst_ + in1); \
    } else { \
        gload16(Ab + (size_t)r0_ * LDA + colb_ + c0_, dst_ + in0); \
        gload16(Ab + (size_t)r1_ * LDA + colb_ + c1_, dst_ + in1); \
    } \
} while (0)

// ONE barrier per phase. 16 MFMA per barrier.
#define PHASE8(ph, kt2, VC) do { \
    constexpr int kk_ = (((ph) - 1) >> 1) & 1; \
    constexpr int mh_ = ((ph) - 1) & 1; \
    constexpr int rbuf_ = ((ph) <= 4) ? 0 : 1; \
    constexpr int aro_ = kk_ ? AR1 : AR0; \
    constexpr int bro_ = kk_ ? BR1 : BR0; \
    s16x8 aq[4]; \
    if (mh_ == 0) { \
        _Pragma("unroll") \
        for (int nj = 0; nj < NJ; ++nj) \
            bqr[nj] = *(const s16x8*)(lb + rbuf_ * BUFSZ + bro_ + boff + nj * 1024); \
    } \
    _Pragma("unroll") \
    for (int i = 0; i < 4; ++i) \
        aq[i] = *(const s16x8*)(lb + rbuf_ * BUFSZ + aro_ + aoff + (mh_ * 4 + i) * 1024); \
    { const int g_ = (kt2) * 8 + (ph) + 6; if (g_ <= TOTAL_H) STAGE_H(g_); } \
    asm volatile("s_waitcnt lgkmcnt(0)" ::: "memory"); \
    __builtin_amdgcn_sched_barrier(0); \
    __builtin_amdgcn_s_setprio(1); \
    _Pragma("unroll") \
    for (int i = 0; i < 4; ++i) { \
        _Pragma("unroll") \
        for (int nj = 0; nj < NJ; ++nj) \
            acc[mh_ * 4 + i][nj] = __builtin_amdgcn_mfma_f32_16x16x32_bf16( \
                aq[i], bqr[nj], acc[mh_ * 4 + i][nj], 0, 0, 0); \
    } \
    __builtin_amdgcn_s_setprio(0); \
    if ((ph) == 4 || (ph) == 8) asm volatile("s_waitcnt vmcnt(" #VC ")" ::: "memory"); \
    __builtin_amdgcn_s_barrier(); \
} while (0)

// merged schedule (MODE 1): 4 phases per kt2, one barrier each.
#define MPHASE(q, kt2, VC) do { \
    constexpr int kk_ = ((q) - 1) & 1; \
    constexpr int rbuf_ = ((q) <= 2) ? 0 : 1; \
    constexpr int aro_ = kk_ ? AR1 : AR0; \
    constexpr int bro_ = kk_ ? BR1 : BR0; \
    s16x8 aq[8]; \
    _Pragma("unroll") \
    for (int nj = 0; nj < NJ; ++nj) \
        bqr[nj] = *(const s16x8*)(lb + rbuf_ * BUFSZ + bro_ + boff + nj * 1024); \
    _Pragma("unroll") \
    for (int i = 0; i < 8; ++i) \
        aq[i] = *(const s16x8*)(lb + rbuf_ * BUFSZ + aro_ + aoff + i * 1024); \
    { const int g1_ = (kt2) * 8 + 2 * (q) + 5; if (g1_ <= TOTAL_H) STAGE_H(g1_); \
      const int g2_ = g1_ + 1;                 if (g2_ <= TOTAL_H) STAGE_H(g2_); } \
    asm volatile("s_waitcnt lgkmcnt(0)" ::: "memory"); \
    __builtin_amdgcn_sched_barrier(0); \
    __builtin_amdgcn_s_setprio(1); \
    _Pragma("unroll") \
    for (int i = 0; i < 8; ++i) { \
        _Pragma("unroll") \
        for (int nj = 0; nj < NJ; ++nj) \
            acc[i][nj] = __builtin_amdgcn_mfma_f32_16x16x32_bf16( \
                aq[i], bqr[nj], acc[i][nj], 0, 0, 0); \
    } \
    __builtin_amdgcn_s_setprio(0); \
    if ((q) == 2 || (q) == 4) asm volatile("s_waitcnt vmcnt(" #VC ")" ::: "memory"); \
    __builtin_amdgcn_s_barrier(); \
} while (0)

    // prologue: stage halves 1..6; ensure tile 1 (halves 1-4) complete
    STAGE_H(1); STAGE_H(2); STAGE_H(3); STAGE_H(4); STAGE_H(5); STAGE_H(6);
    if constexpr (MODE == 1) asm volatile("s_waitcnt vmcnt(3)" ::: "memory");
    else                     asm volatile("s_waitcnt vmcnt(4)" ::: "memory");
    __builtin_amdgcn_s_barrier();

    if constexpr (MODE == 1) {
        for (int kt2 = 0; kt2 < NTILES / 2 - 1; ++kt2) {
            MPHASE(1, kt2, 3); MPHASE(2, kt2, 3); MPHASE(3, kt2, 3); MPHASE(4, kt2, 3);
        }
        { const int kt2 = NTILES / 2 - 1;
          MPHASE(1, kt2, 0); MPHASE(2, kt2, 0); MPHASE(3, kt2, 0); MPHASE(4, kt2, 0); }
    } else {
        for (int kt2 = 0; kt2 < NTILES / 2 - 1; ++kt2) {
            PHASE8(1, kt2, 4); PHASE8(2, kt2, 4); PHASE8(3, kt2, 4); PHASE8(4, kt2, 4);
            PHASE8(5, kt2, 4); PHASE8(6, kt2, 4); PHASE8(7, kt2, 4); PHASE8(8, kt2, 4);
        }
        { const int kt2 = NTILES / 2 - 1;
          PHASE8(1, kt2, 0); PHASE8(2, kt2, 0); PHASE8(3, kt2, 0); PHASE8(4, kt2, 0);
          PHASE8(5, kt2, 0); PHASE8(6, kt2, 0); PHASE8(7, kt2, 0); PHASE8(8, kt2, 0); }
    }

    // epilogue: C/D layout col = lane&15, row = (lane>>4)*4 + r
    const int er0 = m0 + wr * 128 + (l >> 4) * 4;
    const int ec0 = n0 + wc * WN + lm;
#pragma unroll
    for (int mi = 0; mi < 8; ++mi) {
#pragma unroll
        for (int nj = 0; nj < NJ; ++nj) {
#pragma unroll
            for (int r = 0; r < 4; ++r) {
                const int row = er0 + mi * 16 + r;
                const int col = ec0 + nj * 16;
                if constexpr (MODE == 2) {
                    const float v = (acc[mi][nj][r] + bias[biasRow ? row : col]) * scale;
                    ((ushort*)Cc)[(size_t)row * ldc_ + col] = f2bf(v);
                } else {
                    ((_Float16*)Cc)[(size_t)row * ldc_ + col] = (_Float16)acc[mi][nj][r];
                }
            }
        }
    }
#undef MPHASE
#undef PHASE8
#undef STAGE_H
#undef ROFFX
}

// ---------------------------------------------------------------------------
// Row softmax: S (fp16) -> P (bf16) in-place, fp32 math.
// ---------------------------------------------------------------------------
__global__ __launch_bounds__(256) void softmax_rows(void* __restrict__ Sbase) {
    const int row = blockIdx.x;
    const int tid = threadIdx.x;
    const _Float16* srow = (const _Float16*)Sbase + (size_t)row * SEQ;

    float f[16];
#pragma unroll
    for (int j = 0; j < 2; ++j) {
        h16x8 v = *(const h16x8*)(srow + (size_t)(tid + j * 256) * 8);
#pragma unroll
        for (int e = 0; e < 8; ++e) f[j * 8 + e] = (float)v[e];
    }

    float m = f[0];
#pragma unroll
    for (int i = 1; i < 16; ++i) m = fmaxf(m, f[i]);
#pragma unroll
    for (int off = 32; off > 0; off >>= 1) m = fmaxf(m, __shfl_xor(m, off));

    __shared__ float redm[4], reds[4];
    const int w = tid >> 6, l = tid & 63;
    if (l == 0) redm[w] = m;
    __syncthreads();
    m = fmaxf(fmaxf(redm[0], redm[1]), fmaxf(redm[2], redm[3]));

    float s = 0.f;
#pragma unroll
    for (int i = 0; i < 16; ++i) { f[i] = __expf(f[i] - m); s += f[i]; }
#pragma unroll
    for (int off = 32; off > 0; off >>= 1) s += __shfl_xor(s, off);
    if (l == 0) reds[w] = s;
    __syncthreads();
    s = (reds[0] + reds[1]) + (reds[2] + reds[3]);
    const float inv = 1.0f / s;

    ushort* prow = (ushort*)Sbase + (size_t)row * SEQ;
#pragma unroll
    for (int j = 0; j < 2; ++j) {
        s16x8 o;
#pragma unroll
        for (int e = 0; e < 8; ++e) o[e] = (short)f2bf(f[j * 8 + e] * inv);
        *(s16x8*)(prow + (size_t)(tid + j * 256) * 8) = o;
    }
}

// ---------------------------------------------------------------------------
// split-K reduce: out[j] = p0[j] + p1[j]  (f16 partials -> f32)
// ---------------------------------------------------------------------------
__global__ __launch_bounds__(256)
void reduce2(const _Float16* __restrict__ p0, const _Float16* __restrict__ p1,
             float* __restrict__ out)
{
    const size_t i = (size_t)(blockIdx.x * 256 + threadIdx.x) * 8;
    h16x8 a = *(const h16x8*)(p0 + i);
    h16x8 b = *(const h16x8*)(p1 + i);
    float4 o0, o1;
    o0.x = (float)a[0] + (float)b[0]; o0.y = (float)a[1] + (float)b[1];
    o0.z = (float)a[2] + (float)b[2]; o0.w = (float)a[3] + (float)b[3];
    o1.x = (float)a[4] + (float)b[4]; o1.y = (float)a[5] + (float)b[5];
    o1.z = (float)a[6] + (float)b[6]; o1.w = (float)a[7] + (float)b[7];
    *(float4*)(out + i) = o0;
    *(float4*)(out + i + 4) = o1;
}

// ---------------------------------------------------------------------------
extern "C" void kernel_launch(void* const* d_in, const int* in_sizes, int n_in,
                              void* d_out, int out_size, void* d_ws, size_t ws_size,
                              hipStream_t stream)
{
    const float* x  = (const float*)d_in[0];
    const float* wq = (const float*)d_in[1];
    const float* bq = (const float*)d_in[2];
    const float* wk = (const float*)d_in[3];
    const float* bk = (const float*)d_in[4];
    const float* wv = (const float*)d_in[5];
    const float* bv = (const float*)d_in[6];

    char* ws = (char*)d_ws;
    const size_t MB = 1024 * 1024;
    // layout (56 MB):
    //  [0,8)   Qb bf16 [4096][1024] -> PV partial 0 (f16) after scores
    //  [8,16)  Kb bf16              -> PV partial 1 (f16) after scores
    //  [16,24) Vt bf16 [1024][4096]
    //  [24,56) S  f16  [4096][4096] -> P bf16 in-place
    //  [24,32) xb bf16 (dead before S written); [32,38) weights bf16 (dead)
    ushort*   Qb  = (ushort*)(ws);
    ushort*   Kb  = (ushort*)(ws + 8 * MB);
    ushort*   Vt  = (ushort*)(ws + 16 * MB);
    void*     Sm  = (void*)(ws + 24 * MB);
    ushort*   P   = (ushort*)(ws + 24 * MB);
    ushort*   xb  = (ushort*)(ws + 24 * MB);
    ushort*   wqb = (ushort*)(ws + 32 * MB);
    ushort*   wkb = (ushort*)(ws + 34 * MB);
    ushort*   wvb = (ushort*)(ws + 36 * MB);
    _Float16* Pp  = (_Float16*)(ws);            // partials: ks * 4M f16 elems

    // 1) converts (one launch)
    cvt_all<<<dim3(7168), dim3(256), 0, stream>>>(x, wq, wk, wv, xb, wqb, wkb, wvb);

    // 2) fused QKV: Q=(x wq^T + bq)/32, K=x wk^T + bk, Vt=wv x^T + bv[row]
    gemm256p<2><<<dim3(192), dim3(512), 0, stream>>>(
        xb, wqb, Qb, xb, wkb, Kb, wvb, xb, Vt, bq, bk, bv);

    // 3) scores: S = Qs @ K^T (f16), 8-phase 256^2
    gemm256p<0><<<dim3(256), dim3(512), 0, stream>>>(
        Qb, Kb, Sm, nullptr, nullptr, nullptr, nullptr, nullptr, nullptr,
        nullptr, nullptr, nullptr);

    // 4) softmax rows (in-place f16 -> bf16)
    softmax_rows<<<dim3(SEQ), dim3(256), 0, stream>>>(Sm);

    // 5) PV split-K=2, merged-phase 256x128 -> f16 partials in [0,16) MB
    gemm256p<1><<<dim3(256), dim3(512), 0, stream>>>(
        P, Vt, Pp, nullptr, nullptr, nullptr, nullptr, nullptr, nullptr,
        nullptr, nullptr, nullptr);

    // 6) reduce partials -> f32 d_out
    reduce2<<<dim3(2048), dim3(256), 0, stream>>>(Pp, Pp + (size_t)4096 * 1024,
                                                  (float*)d_out);
}

// Round 11
// 133.089 us; speedup vs baseline: 1.0423x; 1.0423x over previous
//
#include <hip/hip_runtime.h>
#include <hip/hip_bf16.h>
#include <stdint.h>

#define SEQ 4096
#define DM  1024

typedef __attribute__((ext_vector_type(8))) short  s16x8;
typedef __attribute__((ext_vector_type(8))) _Float16 h16x8;
typedef __attribute__((ext_vector_type(4))) float  f32x4;

__device__ __forceinline__ ushort f2bf(float f) {
    union { float f; uint32_t u; } x; x.f = f;
    uint32_t r = x.u + 0x7fffu + ((x.u >> 16) & 1u);
    return (ushort)(r >> 16);
}

__device__ __forceinline__ void gload16(const void* g, void* l) {
    __builtin_amdgcn_global_load_lds(
        (const __attribute__((address_space(1))) void*)g,
        (__attribute__((address_space(3))) void*)l,
        16, 0, 0);
}

// ---------------------------------------------------------------------------
// fused fp32->bf16 convert of x + wq + wk + wv (one launch)
// ---------------------------------------------------------------------------
__global__ __launch_bounds__(256)
void cvt_all(const float* __restrict__ x,  const float* __restrict__ wq,
             const float* __restrict__ wk, const float* __restrict__ wv,
             ushort* __restrict__ xb,  ushort* __restrict__ wqb,
             ushort* __restrict__ wkb, ushort* __restrict__ wvb)
{
    int i = blockIdx.x * 256 + threadIdx.x;      // grid sized exactly (7168*256)
    const float* src; ushort* dst; int k;
    if (i < 1048576) { src = x; dst = xb; k = i; }
    else {
        int j = i - 1048576; int w = j >> 18; k = j & 262143;
        src = (w == 0) ? wq : (w == 1) ? wk : wv;
        dst = (w == 0) ? wqb : (w == 1) ? wkb : wvb;
    }
    float4 v = ((const float4*)src)[k];
    ushort4 o;
    o.x = f2bf(v.x); o.y = f2bf(v.y); o.z = f2bf(v.z); o.w = f2bf(v.w);
    ((ushort4*)dst)[k] = o;
}

// ===========================================================================
// 8-phase 256-row GEMM template (C = A[M,K] * B[N,K]^T, bf16 in).
// MODE 0: scores — BN=256, LDA=1024, 16 K-tiles, grid 256, f16 out.
// MODE 1: PV split-K=2 — BN=128, LDA=4096, 32 K-tiles/slice, grid 256,
//         f16 partials; merged phases (16 MFMA per barrier).
// MODE 2: fused QKV — BN=256, LDA=1024, grid 192, bf16 out + bias/scale.
// Round-11: A/B isolation vs round 9 — swizzle REVERTED to the proven
// st_16x32 involution (bit5 ^= bit9; 0 bank conflicts measured rounds 7-9);
// one-barrier-per-phase KEPT (only variable vs round 9).
// ===========================================================================
template<int MODE>
__global__ __launch_bounds__(512, 1)
void gemm256p(const ushort* __restrict__ pA,  const ushort* __restrict__ pB,  void* __restrict__ pC,
              const ushort* __restrict__ pA2, const ushort* __restrict__ pB2, void* __restrict__ pC2,
              const ushort* __restrict__ pA3, const ushort* __restrict__ pB3, void* __restrict__ pC3,
              const float* __restrict__ pb1,  const float* __restrict__ pb2,  const float* __restrict__ pb3)
{
    constexpr int BN      = (MODE == 1) ? 128 : 256;
    constexpr int WN      = BN / 4;
    constexpr int NJ      = BN / 64;
    constexpr int LDA     = (MODE == 1) ? 4096 : 1024;
    constexpr int REG_A   = 16384;               // A half-tile bytes [256][32]
    constexpr int REG_B   = BN * 64;             // B half-tile bytes [BN][32]
    constexpr int BUFSZ   = 2 * (REG_A + REG_B);
    constexpr int NTILES  = (MODE == 1) ? 32 : 16;
    constexpr int TOTAL_H = NTILES * 4;
    constexpr int NWG     = (MODE == 2) ? 192 : 256;

    __shared__ alignas(16) char lb[2 * BUFSZ];

    const int wg = blockIdx.x;
    const int logical = (wg & 7) * (NWG / 8) + (wg >> 3);

    int m0, n0, ldc_ = 0, biasRow = 0;
    const ushort *Ab, *Bb;
    char* Cc;
    const float* bias = nullptr;
    float scale = 1.0f;

    if constexpr (MODE == 0) {
        const int bx = logical & 15, by = logical >> 4;
        m0 = by * 256; n0 = bx * 256;
        Ab = pA + (size_t)m0 * LDA; Bb = pB + (size_t)n0 * LDA;
        Cc = (char*)pC; ldc_ = 4096;
    } else if constexpr (MODE == 1) {
        const int t = logical >> 1, ks = logical & 1;
        m0 = (t >> 3) * 256; n0 = (t & 7) * 128;
        Ab = pA + (size_t)m0 * LDA + ks * 2048;
        Bb = pB + (size_t)n0 * LDA + ks * 2048;
        Cc = (char*)pC + (size_t)ks * 8388608u;  // 4096*1024 f16 elems
        ldc_ = 1024;
    } else {
        const int which = logical / 64, t = logical % 64;
        if (which == 0)      { m0 = (t >> 2) * 256; n0 = (t & 3) * 256;  Ab = pA;  Bb = pB;  Cc = (char*)pC;  bias = pb1; scale = 0.03125f; ldc_ = 1024; }
        else if (which == 1) { m0 = (t >> 2) * 256; n0 = (t & 3) * 256;  Ab = pA2; Bb = pB2; Cc = (char*)pC2; bias = pb2; ldc_ = 1024; }
        else                 { m0 = (t >> 4) * 256; n0 = (t & 15) * 256; Ab = pA3; Bb = pB3; Cc = (char*)pC3; bias = pb3; biasRow = 1; ldc_ = 4096; }
        Ab += (size_t)m0 * LDA; Bb += (size_t)n0 * LDA;
    }

    const int tid = threadIdx.x;
    const int w = tid >> 6, l = tid & 63;
    const int wr = w >> 2, wc = w & 3;
    const int lm = l & 15;
    const int khb = (l >> 4) * 16;

    // staging decode: LDS linear dst; pre-swizzled global src (bit5 ^= bit9)
    const int in0 = tid * 16, in1 = 8192 + tid * 16;
    const int b0 = in0 ^ (((in0 >> 9) & 1) << 5);
    const int b1 = in1 ^ (((in1 >> 9) & 1) << 5);
    const int r0_ = b0 >> 6, c0_ = (b0 & 63) >> 1;
    const int r1_ = b1 >> 6, c1_ = (b1 & 63) >> 1;

    // ds-read bases; swizzle bit depends only on lm bit3 (involution)
    const int swzb = ((lm >> 3) & 1) << 5;
    const int aoff = (((wr * 128 + lm) * 64 + khb) ^ swzb);
    const int boff = (((wc * WN  + lm) * 64 + khb) ^ swzb);

    f32x4 acc[8][NJ] = {};
    s16x8 bqr[NJ];

    // region byte offsets within a buffer: A0, B0, A1, B1
    constexpr int AR0 = 0, BR0 = REG_A, AR1 = REG_A + REG_B, BR1 = 2 * REG_A + REG_B;

#define ROFFX(reg_) ((reg_) == 0 ? AR0 : (reg_) == 1 ? BR0 : (reg_) == 2 ? AR1 : BR1)

#define STAGE_H(g) do { \
    const int hidx_ = (g) - 1, tile_ = hidx_ >> 2, reg_ = hidx_ & 3; \
    const int colb_ = tile_ * 64 + (reg_ >> 1) * 32; \
    char* dst_ = lb + (tile_ & 1) * BUFSZ + ROFFX(reg_); \
    if (reg_ & 1) { \
        gload16(Bb + (size_t)r0_ * LDA + colb_ + c0_, dst_ + in0); \
        if (BN == 256) gload16(Bb + (size_t)r1_ * LDA + colb_ + c1_, dst_ + in1); \
    } else { \
        gload16(Ab + (size_t)r0_ * LDA + colb_ + c0_, dst_ + in0); \
        gload16(Ab + (size_t)r1_ * LDA + colb_ + c1_, dst_ + in1); \
    } \
} while (0)

// ONE barrier per phase. 16 MFMA per barrier (BN=256 modes).
#define PHASE8(ph, kt2, VC) do { \
    constexpr int kk_ = (((ph) - 1) >> 1) & 1; \
    constexpr int mh_ = ((ph) - 1) & 1; \
    constexpr int rbuf_ = ((ph) <= 4) ? 0 : 1; \
    constexpr int aro_ = kk_ ? AR1 : AR0; \
    constexpr int bro_ = kk_ ? BR1 : BR0; \
    s16x8 aq[4]; \
    if (mh_ == 0) { \
        _Pragma("unroll") \
        for (int nj = 0; nj < NJ; ++nj) \
            bqr[nj] = *(const s16x8*)(lb + rbuf_ * BUFSZ + bro_ + boff + nj * 1024); \
    } \
    _Pragma("unroll") \
    for (int i = 0; i < 4; ++i) \
        aq[i] = *(const s16x8*)(lb + rbuf_ * BUFSZ + aro_ + aoff + (mh_ * 4 + i) * 1024); \
    { const int g_ = (kt2) * 8 + (ph) + 6; if (g_ <= TOTAL_H) STAGE_H(g_); } \
    asm volatile("s_waitcnt lgkmcnt(0)" ::: "memory"); \
    __builtin_amdgcn_sched_barrier(0); \
    __builtin_amdgcn_s_setprio(1); \
    _Pragma("unroll") \
    for (int i = 0; i < 4; ++i) { \
        _Pragma("unroll") \
        for (int nj = 0; nj < NJ; ++nj) \
            acc[mh_ * 4 + i][nj] = __builtin_amdgcn_mfma_f32_16x16x32_bf16( \
                aq[i], bqr[nj], acc[mh_ * 4 + i][nj], 0, 0, 0); \
    } \
    __builtin_amdgcn_s_setprio(0); \
    if ((ph) == 4 || (ph) == 8) asm volatile("s_waitcnt vmcnt(" #VC ")" ::: "memory"); \
    __builtin_amdgcn_s_barrier(); \
} while (0)

// merged schedule (MODE 1): 4 phases per kt2, one barrier each.
#define MPHASE(q, kt2, VC) do { \
    constexpr int kk_ = ((q) - 1) & 1; \
    constexpr int rbuf_ = ((q) <= 2) ? 0 : 1; \
    constexpr int aro_ = kk_ ? AR1 : AR0; \
    constexpr int bro_ = kk_ ? BR1 : BR0; \
    s16x8 aq[8]; \
    _Pragma("unroll") \
    for (int nj = 0; nj < NJ; ++nj) \
        bqr[nj] = *(const s16x8*)(lb + rbuf_ * BUFSZ + bro_ + boff + nj * 1024); \
    _Pragma("unroll") \
    for (int i = 0; i < 8; ++i) \
        aq[i] = *(const s16x8*)(lb + rbuf_ * BUFSZ + aro_ + aoff + i * 1024); \
    { const int g1_ = (kt2) * 8 + 2 * (q) + 5; if (g1_ <= TOTAL_H) STAGE_H(g1_); \
      const int g2_ = g1_ + 1;                 if (g2_ <= TOTAL_H) STAGE_H(g2_); } \
    asm volatile("s_waitcnt lgkmcnt(0)" ::: "memory"); \
    __builtin_amdgcn_sched_barrier(0); \
    __builtin_amdgcn_s_setprio(1); \
    _Pragma("unroll") \
    for (int i = 0; i < 8; ++i) { \
        _Pragma("unroll") \
        for (int nj = 0; nj < NJ; ++nj) \
            acc[i][nj] = __builtin_amdgcn_mfma_f32_16x16x32_bf16( \
                aq[i], bqr[nj], acc[i][nj], 0, 0, 0); \
    } \
    __builtin_amdgcn_s_setprio(0); \
    if ((q) == 2 || (q) == 4) asm volatile("s_waitcnt vmcnt(" #VC ")" ::: "memory"); \
    __builtin_amdgcn_s_barrier(); \
} while (0)

    // prologue: stage halves 1..6; ensure tile 1 (halves 1-4) complete
    STAGE_H(1); STAGE_H(2); STAGE_H(3); STAGE_H(4); STAGE_H(5); STAGE_H(6);
    if constexpr (MODE == 1) asm volatile("s_waitcnt vmcnt(3)" ::: "memory");
    else                     asm volatile("s_waitcnt vmcnt(4)" ::: "memory");
    __builtin_amdgcn_s_barrier();

    if constexpr (MODE == 1) {
        for (int kt2 = 0; kt2 < NTILES / 2 - 1; ++kt2) {
            MPHASE(1, kt2, 3); MPHASE(2, kt2, 3); MPHASE(3, kt2, 3); MPHASE(4, kt2, 3);
        }
        { const int kt2 = NTILES / 2 - 1;
          MPHASE(1, kt2, 0); MPHASE(2, kt2, 0); MPHASE(3, kt2, 0); MPHASE(4, kt2, 0); }
    } else {
        for (int kt2 = 0; kt2 < NTILES / 2 - 1; ++kt2) {
            PHASE8(1, kt2, 4); PHASE8(2, kt2, 4); PHASE8(3, kt2, 4); PHASE8(4, kt2, 4);
            PHASE8(5, kt2, 4); PHASE8(6, kt2, 4); PHASE8(7, kt2, 4); PHASE8(8, kt2, 4);
        }
        { const int kt2 = NTILES / 2 - 1;
          PHASE8(1, kt2, 0); PHASE8(2, kt2, 0); PHASE8(3, kt2, 0); PHASE8(4, kt2, 0);
          PHASE8(5, kt2, 0); PHASE8(6, kt2, 0); PHASE8(7, kt2, 0); PHASE8(8, kt2, 0); }
    }

    // epilogue: C/D layout col = lane&15, row = (lane>>4)*4 + r
    const int er0 = m0 + wr * 128 + (l >> 4) * 4;
    const int ec0 = n0 + wc * WN + lm;
#pragma unroll
    for (int mi = 0; mi < 8; ++mi) {
#pragma unroll
        for (int nj = 0; nj < NJ; ++nj) {
#pragma unroll
            for (int r = 0; r < 4; ++r) {
                const int row = er0 + mi * 16 + r;
                const int col = ec0 + nj * 16;
                if constexpr (MODE == 2) {
                    const float v = (acc[mi][nj][r] + bias[biasRow ? row : col]) * scale;
                    ((ushort*)Cc)[(size_t)row * ldc_ + col] = f2bf(v);
                } else {
                    ((_Float16*)Cc)[(size_t)row * ldc_ + col] = (_Float16)acc[mi][nj][r];
                }
            }
        }
    }
#undef MPHASE
#undef PHASE8
#undef STAGE_H
#undef ROFFX
}

// ---------------------------------------------------------------------------
// Row softmax: S (fp16) -> P (bf16) in-place, fp32 math.
// ---------------------------------------------------------------------------
__global__ __launch_bounds__(256) void softmax_rows(void* __restrict__ Sbase) {
    const int row = blockIdx.x;
    const int tid = threadIdx.x;
    const _Float16* srow = (const _Float16*)Sbase + (size_t)row * SEQ;

    float f[16];
#pragma unroll
    for (int j = 0; j < 2; ++j) {
        h16x8 v = *(const h16x8*)(srow + (size_t)(tid + j * 256) * 8);
#pragma unroll
        for (int e = 0; e < 8; ++e) f[j * 8 + e] = (float)v[e];
    }

    float m = f[0];
#pragma unroll
    for (int i = 1; i < 16; ++i) m = fmaxf(m, f[i]);
#pragma unroll
    for (int off = 32; off > 0; off >>= 1) m = fmaxf(m, __shfl_xor(m, off));

    __shared__ float redm[4], reds[4];
    const int w = tid >> 6, l = tid & 63;
    if (l == 0) redm[w] = m;
    __syncthreads();
    m = fmaxf(fmaxf(redm[0], redm[1]), fmaxf(redm[2], redm[3]));

    float s = 0.f;
#pragma unroll
    for (int i = 0; i < 16; ++i) { f[i] = __expf(f[i] - m); s += f[i]; }
#pragma unroll
    for (int off = 32; off > 0; off >>= 1) s += __shfl_xor(s, off);
    if (l == 0) reds[w] = s;
    __syncthreads();
    s = (reds[0] + reds[1]) + (reds[2] + reds[3]);
    const float inv = 1.0f / s;

    ushort* prow = (ushort*)Sbase + (size_t)row * SEQ;
#pragma unroll
    for (int j = 0; j < 2; ++j) {
        s16x8 o;
#pragma unroll
        for (int e = 0; e < 8; ++e) o[e] = (short)f2bf(f[j * 8 + e] * inv);
        *(s16x8*)(prow + (size_t)(tid + j * 256) * 8) = o;
    }
}

// ---------------------------------------------------------------------------
// split-K reduce: out[j] = p0[j] + p1[j]  (f16 partials -> f32)
// ---------------------------------------------------------------------------
__global__ __launch_bounds__(256)
void reduce2(const _Float16* __restrict__ p0, const _Float16* __restrict__ p1,
             float* __restrict__ out)
{
    const size_t i = (size_t)(blockIdx.x * 256 + threadIdx.x) * 8;
    h16x8 a = *(const h16x8*)(p0 + i);
    h16x8 b = *(const h16x8*)(p1 + i);
    float4 o0, o1;
    o0.x = (float)a[0] + (float)b[0]; o0.y = (float)a[1] + (float)b[1];
    o0.z = (float)a[2] + (float)b[2]; o0.w = (float)a[3] + (float)b[3];
    o1.x = (float)a[4] + (float)b[4]; o1.y = (float)a[5] + (float)b[5];
    o1.z = (float)a[6] + (float)b[6]; o1.w = (float)a[7] + (float)b[7];
    *(float4*)(out + i) = o0;
    *(float4*)(out + i + 4) = o1;
}

// ---------------------------------------------------------------------------
extern "C" void kernel_launch(void* const* d_in, const int* in_sizes, int n_in,
                              void* d_out, int out_size, void* d_ws, size_t ws_size,
                              hipStream_t stream)
{
    const float* x  = (const float*)d_in[0];
    const float* wq = (const float*)d_in[1];
    const float* bq = (const float*)d_in[2];
    const float* wk = (const float*)d_in[3];
    const float* bk = (const float*)d_in[4];
    const float* wv = (const float*)d_in[5];
    const float* bv = (const float*)d_in[6];

    char* ws = (char*)d_ws;
    const size_t MB = 1024 * 1024;
    // layout (56 MB):
    //  [0,8)   Qb bf16 [4096][1024] -> PV partial 0 (f16) after scores
    //  [8,16)  Kb bf16              -> PV partial 1 (f16) after scores
    //  [16,24) Vt bf16 [1024][4096]
    //  [24,56) S  f16  [4096][4096] -> P bf16 in-place
    //  [24,32) xb bf16 (dead before S written); [32,38) weights bf16 (dead)
    ushort*   Qb  = (ushort*)(ws);
    ushort*   Kb  = (ushort*)(ws + 8 * MB);
    ushort*   Vt  = (ushort*)(ws + 16 * MB);
    void*     Sm  = (void*)(ws + 24 * MB);
    ushort*   P   = (ushort*)(ws + 24 * MB);
    ushort*   xb  = (ushort*)(ws + 24 * MB);
    ushort*   wqb = (ushort*)(ws + 32 * MB);
    ushort*   wkb = (ushort*)(ws + 34 * MB);
    ushort*   wvb = (ushort*)(ws + 36 * MB);
    _Float16* Pp  = (_Float16*)(ws);            // partials: ks * 4M f16 elems

    // 1) converts (one launch)
    cvt_all<<<dim3(7168), dim3(256), 0, stream>>>(x, wq, wk, wv, xb, wqb, wkb, wvb);

    // 2) fused QKV: Q=(x wq^T + bq)/32, K=x wk^T + bk, Vt=wv x^T + bv[row]
    gemm256p<2><<<dim3(192), dim3(512), 0, stream>>>(
        xb, wqb, Qb, xb, wkb, Kb, wvb, xb, Vt, bq, bk, bv);

    // 3) scores: S = Qs @ K^T (f16), 8-phase 256^2
    gemm256p<0><<<dim3(256), dim3(512), 0, stream>>>(
        Qb, Kb, Sm, nullptr, nullptr, nullptr, nullptr, nullptr, nullptr,
        nullptr, nullptr, nullptr);

    // 4) softmax rows (in-place f16 -> bf16)
    softmax_rows<<<dim3(SEQ), dim3(256), 0, stream>>>(Sm);

    // 5) PV split-K=2, merged-phase 256x128 -> f16 partials in [0,16) MB
    gemm256p<1><<<dim3(256), dim3(512), 0, stream>>>(
        P, Vt, Pp, nullptr, nullptr, nullptr, nullptr, nullptr, nullptr,
        nullptr, nullptr, nullptr);

    // 6) reduce partials -> f32 d_out
    reduce2<<<dim3(2048), dim3(256), 0, stream>>>(Pp, Pp + (size_t)4096 * 1024,
                                                  (float*)d_out);
}

// Round 12
// 132.771 us; speedup vs baseline: 1.0448x; 1.0024x over previous
//
#include <hip/hip_runtime.h>
#include <hip/hip_bf16.h>
#include <stdint.h>

#define SEQ 4096
#define DM  1024

typedef __attribute__((ext_vector_type(8))) short  s16x8;
typedef __attribute__((ext_vector_type(8))) _Float16 h16x8;
typedef __attribute__((ext_vector_type(4))) float  f32x4;

__device__ __forceinline__ ushort f2bf(float f) {
    union { float f; uint32_t u; } x; x.f = f;
    uint32_t r = x.u + 0x7fffu + ((x.u >> 16) & 1u);
    return (ushort)(r >> 16);
}

__device__ __forceinline__ void gload16(const void* g, void* l) {
    __builtin_amdgcn_global_load_lds(
        (const __attribute__((address_space(1))) void*)g,
        (__attribute__((address_space(3))) void*)l,
        16, 0, 0);
}

// ---------------------------------------------------------------------------
// fused fp32->bf16 convert of x + wq + wk + wv (one launch)
// ---------------------------------------------------------------------------
__global__ __launch_bounds__(256)
void cvt_all(const float* __restrict__ x,  const float* __restrict__ wq,
             const float* __restrict__ wk, const float* __restrict__ wv,
             ushort* __restrict__ xb,  ushort* __restrict__ wqb,
             ushort* __restrict__ wkb, ushort* __restrict__ wvb)
{
    int i = blockIdx.x * 256 + threadIdx.x;      // grid sized exactly (7168*256)
    const float* src; ushort* dst; int k;
    if (i < 1048576) { src = x; dst = xb; k = i; }
    else {
        int j = i - 1048576; int w = j >> 18; k = j & 262143;
        src = (w == 0) ? wq : (w == 1) ? wk : wv;
        dst = (w == 0) ? wqb : (w == 1) ? wkb : wvb;
    }
    float4 v = ((const float4*)src)[k];
    ushort4 o;
    o.x = f2bf(v.x); o.y = f2bf(v.y); o.z = f2bf(v.z); o.w = f2bf(v.w);
    ((ushort4*)dst)[k] = o;
}

// ===========================================================================
// 8-phase 256-row GEMM template (C = A[M,K] * B[N,K]^T, bf16 in).
// MODE 0: scores — BN=256, LDA=1024, 16 K-tiles, grid 256, f16 out.
// MODE 1: PV split-K=2 — BN=128, LDA=4096, 32 K-tiles/slice, grid 256,
//         f16 partials; merged phases (16 MFMA per barrier).
// MODE 2: fused QKV — BN=256, LDA=1024, grid 192, bf16 out + bias/scale.
// Round-12 (single variable vs R11): XCD swizzle -> 4x4 tile clusters,
// 2 clusters per XCD (L2 working set ~4MB = L2 size, was ~9MB stripes).
// Schedule, LDS swizzle (proven involution), stagger, vmcnt: UNCHANGED.
// ===========================================================================
template<int MODE>
__global__ __launch_bounds__(512, 1)
void gemm256p(const ushort* __restrict__ pA,  const ushort* __restrict__ pB,  void* __restrict__ pC,
              const ushort* __restrict__ pA2, const ushort* __restrict__ pB2, void* __restrict__ pC2,
              const ushort* __restrict__ pA3, const ushort* __restrict__ pB3, void* __restrict__ pC3,
              const float* __restrict__ pb1,  const float* __restrict__ pb2,  const float* __restrict__ pb3)
{
    constexpr int BN      = (MODE == 1) ? 128 : 256;
    constexpr int WN      = BN / 4;
    constexpr int NJ      = BN / 64;
    constexpr int LDA     = (MODE == 1) ? 4096 : 1024;
    constexpr int REG_A   = 16384;               // A half-tile bytes [256][32]
    constexpr int REG_B   = BN * 64;             // B half-tile bytes [BN][32]
    constexpr int BUFSZ   = 2 * (REG_A + REG_B);
    constexpr int NTILES  = (MODE == 1) ? 32 : 16;
    constexpr int TOTAL_H = NTILES * 4;
    constexpr int NWG     = (MODE == 2) ? 192 : 256;

    __shared__ alignas(16) char lb[2 * BUFSZ];

    const int wg = blockIdx.x;

    int m0, n0, ldc_ = 0, biasRow = 0;
    const ushort *Ab, *Bb;
    char* Cc;
    const float* bias = nullptr;
    float scale = 1.0f;

    if constexpr (MODE == 0) {
        // 4x4 cluster per-XCD swizzle over the 16x16 tile grid
        const int xcd = wg & 7, s = wg >> 3;
        const int cid = xcd * 2 + (s >> 4);      // cluster id 0..15
        const int t   = s & 15;                  // pos within 4x4 cluster
        const int by = (cid >> 2) * 4 + (t >> 2);
        const int bx = (cid & 3) * 4 + (t & 3);
        m0 = by * 256; n0 = bx * 256;
        Ab = pA + (size_t)m0 * LDA; Bb = pB + (size_t)n0 * LDA;
        Cc = (char*)pC; ldc_ = 4096;
    } else if constexpr (MODE == 1) {
        // 4x4 clusters over virtual 16x16 grid (vx = bx*2 + ks)
        const int xcd = wg & 7, s = wg >> 3;
        const int cid = xcd * 2 + (s >> 4);
        const int t   = s & 15;
        const int by = (cid >> 2) * 4 + (t >> 2);
        const int vx = (cid & 3) * 4 + (t & 3);
        const int bx = vx >> 1, ks = vx & 1;
        m0 = by * 256; n0 = bx * 128;
        Ab = pA + (size_t)m0 * LDA + ks * 2048;
        Bb = pB + (size_t)n0 * LDA + ks * 2048;
        Cc = (char*)pC + (size_t)ks * 8388608u;  // 4096*1024 f16 elems
        ldc_ = 1024;
    } else {
        const int logical = (wg & 7) * (NWG / 8) + (wg >> 3);
        const int which = logical / 64, t = logical % 64;
        if (which == 0)      { m0 = (t >> 2) * 256; n0 = (t & 3) * 256;  Ab = pA;  Bb = pB;  Cc = (char*)pC;  bias = pb1; scale = 0.03125f; ldc_ = 1024; }
        else if (which == 1) { m0 = (t >> 2) * 256; n0 = (t & 3) * 256;  Ab = pA2; Bb = pB2; Cc = (char*)pC2; bias = pb2; ldc_ = 1024; }
        else                 { m0 = (t >> 4) * 256; n0 = (t & 15) * 256; Ab = pA3; Bb = pB3; Cc = (char*)pC3; bias = pb3; biasRow = 1; ldc_ = 4096; }
        Ab += (size_t)m0 * LDA; Bb += (size_t)n0 * LDA;
    }

    const int tid = threadIdx.x;
    const int w = tid >> 6, l = tid & 63;
    const int wr = w >> 2, wc = w & 3;
    const int lm = l & 15;
    const int khb = (l >> 4) * 16;

    // staging decode: LDS linear dst; pre-swizzled global src (bit5 ^= bit9)
    const int in0 = tid * 16, in1 = 8192 + tid * 16;
    const int b0 = in0 ^ (((in0 >> 9) & 1) << 5);
    const int b1 = in1 ^ (((in1 >> 9) & 1) << 5);
    const int r0_ = b0 >> 6, c0_ = (b0 & 63) >> 1;
    const int r1_ = b1 >> 6, c1_ = (b1 & 63) >> 1;

    // ds-read bases; swizzle bit depends only on lm bit3 (involution)
    const int swzb = ((lm >> 3) & 1) << 5;
    const int aoff = (((wr * 128 + lm) * 64 + khb) ^ swzb);
    const int boff = (((wc * WN  + lm) * 64 + khb) ^ swzb);

    f32x4 acc[8][NJ] = {};
    s16x8 bqr[NJ];

    // region byte offsets within a buffer: A0, B0, A1, B1
    constexpr int AR0 = 0, BR0 = REG_A, AR1 = REG_A + REG_B, BR1 = 2 * REG_A + REG_B;

#define ROFFX(reg_) ((reg_) == 0 ? AR0 : (reg_) == 1 ? BR0 : (reg_) == 2 ? AR1 : BR1)

#define STAGE_H(g) do { \
    const int hidx_ = (g) - 1, tile_ = hidx_ >> 2, reg_ = hidx_ & 3; \
    const int colb_ = tile_ * 64 + (reg_ >> 1) * 32; \
    char* dst_ = lb + (tile_ & 1) * BUFSZ + ROFFX(reg_); \
    if (reg_ & 1) { \
        gload16(Bb + (size_t)r0_ * LDA + colb_ + c0_, dst_ + in0); \
        if (BN == 256) gload16(Bb + (size_t)r1_ * LDA + colb_ + c1_, dst_ + in1); \
    } else { \
        gload16(Ab + (size_t)r0_ * LDA + colb_ + c0_, dst_ + in0); \
        gload16(Ab + (size_t)r1_ * LDA + colb_ + c1_, dst_ + in1); \
    } \
} while (0)

// ONE barrier per phase. 16 MFMA per barrier (BN=256 modes).
#define PHASE8(ph, kt2, VC) do { \
    constexpr int kk_ = (((ph) - 1) >> 1) & 1; \
    constexpr int mh_ = ((ph) - 1) & 1; \
    constexpr int rbuf_ = ((ph) <= 4) ? 0 : 1; \
    constexpr int aro_ = kk_ ? AR1 : AR0; \
    constexpr int bro_ = kk_ ? BR1 : BR0; \
    s16x8 aq[4]; \
    if (mh_ == 0) { \
        _Pragma("unroll") \
        for (int nj = 0; nj < NJ; ++nj) \
            bqr[nj] = *(const s16x8*)(lb + rbuf_ * BUFSZ + bro_ + boff + nj * 1024); \
    } \
    _Pragma("unroll") \
    for (int i = 0; i < 4; ++i) \
        aq[i] = *(const s16x8*)(lb + rbuf_ * BUFSZ + aro_ + aoff + (mh_ * 4 + i) * 1024); \
    { const int g_ = (kt2) * 8 + (ph) + 6; if (g_ <= TOTAL_H) STAGE_H(g_); } \
    asm volatile("s_waitcnt lgkmcnt(0)" ::: "memory"); \
    __builtin_amdgcn_sched_barrier(0); \
    __builtin_amdgcn_s_setprio(1); \
    _Pragma("unroll") \
    for (int i = 0; i < 4; ++i) { \
        _Pragma("unroll") \
        for (int nj = 0; nj < NJ; ++nj) \
            acc[mh_ * 4 + i][nj] = __builtin_amdgcn_mfma_f32_16x16x32_bf16( \
                aq[i], bqr[nj], acc[mh_ * 4 + i][nj], 0, 0, 0); \
    } \
    __builtin_amdgcn_s_setprio(0); \
    if ((ph) == 4 || (ph) == 8) asm volatile("s_waitcnt vmcnt(" #VC ")" ::: "memory"); \
    __builtin_amdgcn_s_barrier(); \
} while (0)

// merged schedule (MODE 1): 4 phases per kt2, one barrier each.
#define MPHASE(q, kt2, VC) do { \
    constexpr int kk_ = ((q) - 1) & 1; \
    constexpr int rbuf_ = ((q) <= 2) ? 0 : 1; \
    constexpr int aro_ = kk_ ? AR1 : AR0; \
    constexpr int bro_ = kk_ ? BR1 : BR0; \
    s16x8 aq[8]; \
    _Pragma("unroll") \
    for (int nj = 0; nj < NJ; ++nj) \
        bqr[nj] = *(const s16x8*)(lb + rbuf_ * BUFSZ + bro_ + boff + nj * 1024); \
    _Pragma("unroll") \
    for (int i = 0; i < 8; ++i) \
        aq[i] = *(const s16x8*)(lb + rbuf_ * BUFSZ + aro_ + aoff + i * 1024); \
    { const int g1_ = (kt2) * 8 + 2 * (q) + 5; if (g1_ <= TOTAL_H) STAGE_H(g1_); \
      const int g2_ = g1_ + 1;                 if (g2_ <= TOTAL_H) STAGE_H(g2_); } \
    asm volatile("s_waitcnt lgkmcnt(0)" ::: "memory"); \
    __builtin_amdgcn_sched_barrier(0); \
    __builtin_amdgcn_s_setprio(1); \
    _Pragma("unroll") \
    for (int i = 0; i < 8; ++i) { \
        _Pragma("unroll") \
        for (int nj = 0; nj < NJ; ++nj) \
            acc[i][nj] = __builtin_amdgcn_mfma_f32_16x16x32_bf16( \
                aq[i], bqr[nj], acc[i][nj], 0, 0, 0); \
    } \
    __builtin_amdgcn_s_setprio(0); \
    if ((q) == 2 || (q) == 4) asm volatile("s_waitcnt vmcnt(" #VC ")" ::: "memory"); \
    __builtin_amdgcn_s_barrier(); \
} while (0)

    // prologue: stage halves 1..6; ensure tile 1 (halves 1-4) complete
    STAGE_H(1); STAGE_H(2); STAGE_H(3); STAGE_H(4); STAGE_H(5); STAGE_H(6);
    if constexpr (MODE == 1) asm volatile("s_waitcnt vmcnt(3)" ::: "memory");
    else                     asm volatile("s_waitcnt vmcnt(4)" ::: "memory");
    __builtin_amdgcn_s_barrier();

    if constexpr (MODE == 1) {
        for (int kt2 = 0; kt2 < NTILES / 2 - 1; ++kt2) {
            MPHASE(1, kt2, 3); MPHASE(2, kt2, 3); MPHASE(3, kt2, 3); MPHASE(4, kt2, 3);
        }
        { const int kt2 = NTILES / 2 - 1;
          MPHASE(1, kt2, 0); MPHASE(2, kt2, 0); MPHASE(3, kt2, 0); MPHASE(4, kt2, 0); }
    } else {
        for (int kt2 = 0; kt2 < NTILES / 2 - 1; ++kt2) {
            PHASE8(1, kt2, 4); PHASE8(2, kt2, 4); PHASE8(3, kt2, 4); PHASE8(4, kt2, 4);
            PHASE8(5, kt2, 4); PHASE8(6, kt2, 4); PHASE8(7, kt2, 4); PHASE8(8, kt2, 4);
        }
        { const int kt2 = NTILES / 2 - 1;
          PHASE8(1, kt2, 0); PHASE8(2, kt2, 0); PHASE8(3, kt2, 0); PHASE8(4, kt2, 0);
          PHASE8(5, kt2, 0); PHASE8(6, kt2, 0); PHASE8(7, kt2, 0); PHASE8(8, kt2, 0); }
    }

    // epilogue: C/D layout col = lane&15, row = (lane>>4)*4 + r
    const int er0 = m0 + wr * 128 + (l >> 4) * 4;
    const int ec0 = n0 + wc * WN + lm;
#pragma unroll
    for (int mi = 0; mi < 8; ++mi) {
#pragma unroll
        for (int nj = 0; nj < NJ; ++nj) {
#pragma unroll
            for (int r = 0; r < 4; ++r) {
                const int row = er0 + mi * 16 + r;
                const int col = ec0 + nj * 16;
                if constexpr (MODE == 2) {
                    const float v = (acc[mi][nj][r] + bias[biasRow ? row : col]) * scale;
                    ((ushort*)Cc)[(size_t)row * ldc_ + col] = f2bf(v);
                } else {
                    ((_Float16*)Cc)[(size_t)row * ldc_ + col] = (_Float16)acc[mi][nj][r];
                }
            }
        }
    }
#undef MPHASE
#undef PHASE8
#undef STAGE_H
#undef ROFFX
}

// ---------------------------------------------------------------------------
// Row softmax: S (fp16) -> P (bf16) in-place, fp32 math.
// ---------------------------------------------------------------------------
__global__ __launch_bounds__(256) void softmax_rows(void* __restrict__ Sbase) {
    const int row = blockIdx.x;
    const int tid = threadIdx.x;
    const _Float16* srow = (const _Float16*)Sbase + (size_t)row * SEQ;

    float f[16];
#pragma unroll
    for (int j = 0; j < 2; ++j) {
        h16x8 v = *(const h16x8*)(srow + (size_t)(tid + j * 256) * 8);
#pragma unroll
        for (int e = 0; e < 8; ++e) f[j * 8 + e] = (float)v[e];
    }

    float m = f[0];
#pragma unroll
    for (int i = 1; i < 16; ++i) m = fmaxf(m, f[i]);
#pragma unroll
    for (int off = 32; off > 0; off >>= 1) m = fmaxf(m, __shfl_xor(m, off));

    __shared__ float redm[4], reds[4];
    const int w = tid >> 6, l = tid & 63;
    if (l == 0) redm[w] = m;
    __syncthreads();
    m = fmaxf(fmaxf(redm[0], redm[1]), fmaxf(redm[2], redm[3]));

    float s = 0.f;
#pragma unroll
    for (int i = 0; i < 16; ++i) { f[i] = __expf(f[i] - m); s += f[i]; }
#pragma unroll
    for (int off = 32; off > 0; off >>= 1) s += __shfl_xor(s, off);
    if (l == 0) reds[w] = s;
    __syncthreads();
    s = (reds[0] + reds[1]) + (reds[2] + reds[3]);
    const float inv = 1.0f / s;

    ushort* prow = (ushort*)Sbase + (size_t)row * SEQ;
#pragma unroll
    for (int j = 0; j < 2; ++j) {
        s16x8 o;
#pragma unroll
        for (int e = 0; e < 8; ++e) o[e] = (short)f2bf(f[j * 8 + e] * inv);
        *(s16x8*)(prow + (size_t)(tid + j * 256) * 8) = o;
    }
}

// ---------------------------------------------------------------------------
// split-K reduce: out[j] = p0[j] + p1[j]  (f16 partials -> f32)
// ---------------------------------------------------------------------------
__global__ __launch_bounds__(256)
void reduce2(const _Float16* __restrict__ p0, const _Float16* __restrict__ p1,
             float* __restrict__ out)
{
    const size_t i = (size_t)(blockIdx.x * 256 + threadIdx.x) * 8;
    h16x8 a = *(const h16x8*)(p0 + i);
    h16x8 b = *(const h16x8*)(p1 + i);
    float4 o0, o1;
    o0.x = (float)a[0] + (float)b[0]; o0.y = (float)a[1] + (float)b[1];
    o0.z = (float)a[2] + (float)b[2]; o0.w = (float)a[3] + (float)b[3];
    o1.x = (float)a[4] + (float)b[4]; o1.y = (float)a[5] + (float)b[5];
    o1.z = (float)a[6] + (float)b[6]; o1.w = (float)a[7] + (float)b[7];
    *(float4*)(out + i) = o0;
    *(float4*)(out + i + 4) = o1;
}

// ---------------------------------------------------------------------------
extern "C" void kernel_launch(void* const* d_in, const int* in_sizes, int n_in,
                              void* d_out, int out_size, void* d_ws, size_t ws_size,
                              hipStream_t stream)
{
    const float* x  = (const float*)d_in[0];
    const float* wq = (const float*)d_in[1];
    const float* bq = (const float*)d_in[2];
    const float* wk = (const float*)d_in[3];
    const float* bk = (const float*)d_in[4];
    const float* wv = (const float*)d_in[5];
    const float* bv = (const float*)d_in[6];

    char* ws = (char*)d_ws;
    const size_t MB = 1024 * 1024;
    // layout (56 MB):
    //  [0,8)   Qb bf16 [4096][1024] -> PV partial 0 (f16) after scores
    //  [8,16)  Kb bf16              -> PV partial 1 (f16) after scores
    //  [16,24) Vt bf16 [1024][4096]
    //  [24,56) S  f16  [4096][4096] -> P bf16 in-place
    //  [24,32) xb bf16 (dead before S written); [32,38) weights bf16 (dead)
    ushort*   Qb  = (ushort*)(ws);
    ushort*   Kb  = (ushort*)(ws + 8 * MB);
    ushort*   Vt  = (ushort*)(ws + 16 * MB);
    void*     Sm  = (void*)(ws + 24 * MB);
    ushort*   P   = (ushort*)(ws + 24 * MB);
    ushort*   xb  = (ushort*)(ws + 24 * MB);
    ushort*   wqb = (ushort*)(ws + 32 * MB);
    ushort*   wkb = (ushort*)(ws + 34 * MB);
    ushort*   wvb = (ushort*)(ws + 36 * MB);
    _Float16* Pp  = (_Float16*)(ws);            // partials: ks * 4M f16 elems

    // 1) converts (one launch)
    cvt_all<<<dim3(7168), dim3(256), 0, stream>>>(x, wq, wk, wv, xb, wqb, wkb, wvb);

    // 2) fused QKV: Q=(x wq^T + bq)/32, K=x wk^T + bk, Vt=wv x^T + bv[row]
    gemm256p<2><<<dim3(192), dim3(512), 0, stream>>>(
        xb, wqb, Qb, xb, wkb, Kb, wvb, xb, Vt, bq, bk, bv);

    // 3) scores: S = Qs @ K^T (f16), 8-phase 256^2
    gemm256p<0><<<dim3(256), dim3(512), 0, stream>>>(
        Qb, Kb, Sm, nullptr, nullptr, nullptr, nullptr, nullptr, nullptr,
        nullptr, nullptr, nullptr);

    // 4) softmax rows (in-place f16 -> bf16)
    softmax_rows<<<dim3(SEQ), dim3(256), 0, stream>>>(Sm);

    // 5) PV split-K=2, merged-phase 256x128 -> f16 partials in [0,16) MB
    gemm256p<1><<<dim3(256), dim3(512), 0, stream>>>(
        P, Vt, Pp, nullptr, nullptr, nullptr, nullptr, nullptr, nullptr,
        nullptr, nullptr, nullptr);

    // 6) reduce partials -> f32 d_out
    reduce2<<<dim3(2048), dim3(256), 0, stream>>>(Pp, Pp + (size_t)4096 * 1024,
                                                  (float*)d_out);
}

// Round 14
// 132.182 us; speedup vs baseline: 1.0494x; 1.0045x over previous
//
#include <hip/hip_runtime.h>
#include <hip/hip_bf16.h>
#include <stdint.h>

#define SEQ 4096
#define DM  1024

typedef __attribute__((ext_vector_type(8))) short  s16x8;
typedef __attribute__((ext_vector_type(8))) _Float16 h16x8;
typedef __attribute__((ext_vector_type(4))) float  f32x4;

__device__ __forceinline__ ushort f2bf(float f) {
    union { float f; uint32_t u; } x; x.f = f;
    uint32_t r = x.u + 0x7fffu + ((x.u >> 16) & 1u);
    return (ushort)(r >> 16);
}

__device__ __forceinline__ void gload16(const void* g, void* l) {
    __builtin_amdgcn_global_load_lds(
        (const __attribute__((address_space(1))) void*)g,
        (__attribute__((address_space(3))) void*)l,
        16, 0, 0);
}

// ---------------------------------------------------------------------------
// fused fp32->bf16 convert of x + wq + wk + wv (one launch)
// ---------------------------------------------------------------------------
__global__ __launch_bounds__(256)
void cvt_all(const float* __restrict__ x,  const float* __restrict__ wq,
             const float* __restrict__ wk, const float* __restrict__ wv,
             ushort* __restrict__ xb,  ushort* __restrict__ wqb,
             ushort* __restrict__ wkb, ushort* __restrict__ wvb)
{
    int i = blockIdx.x * 256 + threadIdx.x;      // grid sized exactly (7168*256)
    const float* src; ushort* dst; int k;
    if (i < 1048576) { src = x; dst = xb; k = i; }
    else {
        int j = i - 1048576; int w = j >> 18; k = j & 262143;
        src = (w == 0) ? wq : (w == 1) ? wk : wv;
        dst = (w == 0) ? wqb : (w == 1) ? wkb : wvb;
    }
    float4 v = ((const float4*)src)[k];
    ushort4 o;
    o.x = f2bf(v.x); o.y = f2bf(v.y); o.z = f2bf(v.z); o.w = f2bf(v.w);
    ((ushort4*)dst)[k] = o;
}

// ===========================================================================
// 8-phase 256-row GEMM template (C = A[M,K] * B[N,K]^T, bf16 in).
// MODE 0: scores — BN=256, LDA=1024, 16 K-tiles, grid 256, f16 out.
// MODE 1: PV split-K=2 — BN=128, LDA=4096, 32 K-tiles/slice, grid 256,
//         f16 partials; merged phases (16 MFMA per barrier).
// MODE 2: fused QKV — BN=256, LDA=1024, grid 192, bf16 out + bias/scale.
// Round-14: REVERT to R12 exactly (R13's vectorized epilogue failed replay
// validation AND gained 0 time — dropped). Scalar epilogue restored.
// ===========================================================================
template<int MODE>
__global__ __launch_bounds__(512, 1)
void gemm256p(const ushort* __restrict__ pA,  const ushort* __restrict__ pB,  void* __restrict__ pC,
              const ushort* __restrict__ pA2, const ushort* __restrict__ pB2, void* __restrict__ pC2,
              const ushort* __restrict__ pA3, const ushort* __restrict__ pB3, void* __restrict__ pC3,
              const float* __restrict__ pb1,  const float* __restrict__ pb2,  const float* __restrict__ pb3)
{
    constexpr int BN      = (MODE == 1) ? 128 : 256;
    constexpr int WN      = BN / 4;
    constexpr int NJ      = BN / 64;
    constexpr int LDA     = (MODE == 1) ? 4096 : 1024;
    constexpr int REG_A   = 16384;               // A half-tile bytes [256][32]
    constexpr int REG_B   = BN * 64;             // B half-tile bytes [BN][32]
    constexpr int BUFSZ   = 2 * (REG_A + REG_B);
    constexpr int NTILES  = (MODE == 1) ? 32 : 16;
    constexpr int TOTAL_H = NTILES * 4;
    constexpr int NWG     = (MODE == 2) ? 192 : 256;

    __shared__ alignas(16) char lb[2 * BUFSZ];

    const int wg = blockIdx.x;

    int m0, n0, ldc_ = 0, biasRow = 0;
    const ushort *Ab, *Bb;
    char* Cc;
    const float* bias = nullptr;
    float scale = 1.0f;

    if constexpr (MODE == 0) {
        const int xcd = wg & 7, s = wg >> 3;
        const int cid = xcd * 2 + (s >> 4);
        const int t   = s & 15;
        const int by = (cid >> 2) * 4 + (t >> 2);
        const int bx = (cid & 3) * 4 + (t & 3);
        m0 = by * 256; n0 = bx * 256;
        Ab = pA + (size_t)m0 * LDA; Bb = pB + (size_t)n0 * LDA;
        Cc = (char*)pC; ldc_ = 4096;
    } else if constexpr (MODE == 1) {
        const int xcd = wg & 7, s = wg >> 3;
        const int cid = xcd * 2 + (s >> 4);
        const int t   = s & 15;
        const int by = (cid >> 2) * 4 + (t >> 2);
        const int vx = (cid & 3) * 4 + (t & 3);
        const int bx = vx >> 1, ks = vx & 1;
        m0 = by * 256; n0 = bx * 128;
        Ab = pA + (size_t)m0 * LDA + ks * 2048;
        Bb = pB + (size_t)n0 * LDA + ks * 2048;
        Cc = (char*)pC + (size_t)ks * 8388608u;  // 4096*1024 f16 elems
        ldc_ = 1024;
    } else {
        const int logical = (wg & 7) * (NWG / 8) + (wg >> 3);
        const int which = logical / 64, t = logical % 64;
        if (which == 0)      { m0 = (t >> 2) * 256; n0 = (t & 3) * 256;  Ab = pA;  Bb = pB;  Cc = (char*)pC;  bias = pb1; scale = 0.03125f; ldc_ = 1024; }
        else if (which == 1) { m0 = (t >> 2) * 256; n0 = (t & 3) * 256;  Ab = pA2; Bb = pB2; Cc = (char*)pC2; bias = pb2; ldc_ = 1024; }
        else                 { m0 = (t >> 4) * 256; n0 = (t & 15) * 256; Ab = pA3; Bb = pB3; Cc = (char*)pC3; bias = pb3; biasRow = 1; ldc_ = 4096; }
        Ab += (size_t)m0 * LDA; Bb += (size_t)n0 * LDA;
    }

    const int tid = threadIdx.x;
    const int w = tid >> 6, l = tid & 63;
    const int wr = w >> 2, wc = w & 3;
    const int lm = l & 15;
    const int khb = (l >> 4) * 16;

    // staging decode: LDS linear dst; pre-swizzled global src (bit5 ^= bit9)
    const int in0 = tid * 16, in1 = 8192 + tid * 16;
    const int b0 = in0 ^ (((in0 >> 9) & 1) << 5);
    const int b1 = in1 ^ (((in1 >> 9) & 1) << 5);
    const int r0_ = b0 >> 6, c0_ = (b0 & 63) >> 1;
    const int r1_ = b1 >> 6, c1_ = (b1 & 63) >> 1;

    // ds-read bases; swizzle bit depends only on lm bit3 (involution)
    const int swzb = ((lm >> 3) & 1) << 5;
    const int aoff = (((wr * 128 + lm) * 64 + khb) ^ swzb);
    const int boff = (((wc * WN  + lm) * 64 + khb) ^ swzb);

    f32x4 acc[8][NJ] = {};
    s16x8 bqr[NJ];

    // region byte offsets within a buffer: A0, B0, A1, B1
    constexpr int AR0 = 0, BR0 = REG_A, AR1 = REG_A + REG_B, BR1 = 2 * REG_A + REG_B;

#define ROFFX(reg_) ((reg_) == 0 ? AR0 : (reg_) == 1 ? BR0 : (reg_) == 2 ? AR1 : BR1)

#define STAGE_H(g) do { \
    const int hidx_ = (g) - 1, tile_ = hidx_ >> 2, reg_ = hidx_ & 3; \
    const int colb_ = tile_ * 64 + (reg_ >> 1) * 32; \
    char* dst_ = lb + (tile_ & 1) * BUFSZ + ROFFX(reg_); \
    if (reg_ & 1) { \
        gload16(Bb + (size_t)r0_ * LDA + colb_ + c0_, dst_ + in0); \
        if (BN == 256) gload16(Bb + (size_t)r1_ * LDA + colb_ + c1_, dst_ + in1); \
    } else { \
        gload16(Ab + (size_t)r0_ * LDA + colb_ + c0_, dst_ + in0); \
        gload16(Ab + (size_t)r1_ * LDA + colb_ + c1_, dst_ + in1); \
    } \
} while (0)

// ONE barrier per phase. 16 MFMA per barrier (BN=256 modes).
#define PHASE8(ph, kt2, VC) do { \
    constexpr int kk_ = (((ph) - 1) >> 1) & 1; \
    constexpr int mh_ = ((ph) - 1) & 1; \
    constexpr int rbuf_ = ((ph) <= 4) ? 0 : 1; \
    constexpr int aro_ = kk_ ? AR1 : AR0; \
    constexpr int bro_ = kk_ ? BR1 : BR0; \
    s16x8 aq[4]; \
    if (mh_ == 0) { \
        _Pragma("unroll") \
        for (int nj = 0; nj < NJ; ++nj) \
            bqr[nj] = *(const s16x8*)(lb + rbuf_ * BUFSZ + bro_ + boff + nj * 1024); \
    } \
    _Pragma("unroll") \
    for (int i = 0; i < 4; ++i) \
        aq[i] = *(const s16x8*)(lb + rbuf_ * BUFSZ + aro_ + aoff + (mh_ * 4 + i) * 1024); \
    { const int g_ = (kt2) * 8 + (ph) + 6; if (g_ <= TOTAL_H) STAGE_H(g_); } \
    asm volatile("s_waitcnt lgkmcnt(0)" ::: "memory"); \
    __builtin_amdgcn_sched_barrier(0); \
    __builtin_amdgcn_s_setprio(1); \
    _Pragma("unroll") \
    for (int i = 0; i < 4; ++i) { \
        _Pragma("unroll") \
        for (int nj = 0; nj < NJ; ++nj) \
            acc[mh_ * 4 + i][nj] = __builtin_amdgcn_mfma_f32_16x16x32_bf16( \
                aq[i], bqr[nj], acc[mh_ * 4 + i][nj], 0, 0, 0); \
    } \
    __builtin_amdgcn_s_setprio(0); \
    if ((ph) == 4 || (ph) == 8) asm volatile("s_waitcnt vmcnt(" #VC ")" ::: "memory"); \
    __builtin_amdgcn_s_barrier(); \
} while (0)

// merged schedule (MODE 1): 4 phases per kt2, one barrier each.
#define MPHASE(q, kt2, VC) do { \
    constexpr int kk_ = ((q) - 1) & 1; \
    constexpr int rbuf_ = ((q) <= 2) ? 0 : 1; \
    constexpr int aro_ = kk_ ? AR1 : AR0; \
    constexpr int bro_ = kk_ ? BR1 : BR0; \
    s16x8 aq[8]; \
    _Pragma("unroll") \
    for (int nj = 0; nj < NJ; ++nj) \
        bqr[nj] = *(const s16x8*)(lb + rbuf_ * BUFSZ + bro_ + boff + nj * 1024); \
    _Pragma("unroll") \
    for (int i = 0; i < 8; ++i) \
        aq[i] = *(const s16x8*)(lb + rbuf_ * BUFSZ + aro_ + aoff + i * 1024); \
    { const int g1_ = (kt2) * 8 + 2 * (q) + 5; if (g1_ <= TOTAL_H) STAGE_H(g1_); \
      const int g2_ = g1_ + 1;                 if (g2_ <= TOTAL_H) STAGE_H(g2_); } \
    asm volatile("s_waitcnt lgkmcnt(0)" ::: "memory"); \
    __builtin_amdgcn_sched_barrier(0); \
    __builtin_amdgcn_s_setprio(1); \
    _Pragma("unroll") \
    for (int i = 0; i < 8; ++i) { \
        _Pragma("unroll") \
        for (int nj = 0; nj < NJ; ++nj) \
            acc[i][nj] = __builtin_amdgcn_mfma_f32_16x16x32_bf16( \
                aq[i], bqr[nj], acc[i][nj], 0, 0, 0); \
    } \
    __builtin_amdgcn_s_setprio(0); \
    if ((q) == 2 || (q) == 4) asm volatile("s_waitcnt vmcnt(" #VC ")" ::: "memory"); \
    __builtin_amdgcn_s_barrier(); \
} while (0)

    // prologue: stage halves 1..6; ensure tile 1 (halves 1-4) complete
    STAGE_H(1); STAGE_H(2); STAGE_H(3); STAGE_H(4); STAGE_H(5); STAGE_H(6);
    if constexpr (MODE == 1) asm volatile("s_waitcnt vmcnt(3)" ::: "memory");
    else                     asm volatile("s_waitcnt vmcnt(4)" ::: "memory");
    __builtin_amdgcn_s_barrier();

    if constexpr (MODE == 1) {
        for (int kt2 = 0; kt2 < NTILES / 2 - 1; ++kt2) {
            MPHASE(1, kt2, 3); MPHASE(2, kt2, 3); MPHASE(3, kt2, 3); MPHASE(4, kt2, 3);
        }
        { const int kt2 = NTILES / 2 - 1;
          MPHASE(1, kt2, 0); MPHASE(2, kt2, 0); MPHASE(3, kt2, 0); MPHASE(4, kt2, 0); }
    } else {
        for (int kt2 = 0; kt2 < NTILES / 2 - 1; ++kt2) {
            PHASE8(1, kt2, 4); PHASE8(2, kt2, 4); PHASE8(3, kt2, 4); PHASE8(4, kt2, 4);
            PHASE8(5, kt2, 4); PHASE8(6, kt2, 4); PHASE8(7, kt2, 4); PHASE8(8, kt2, 4);
        }
        { const int kt2 = NTILES / 2 - 1;
          PHASE8(1, kt2, 0); PHASE8(2, kt2, 0); PHASE8(3, kt2, 0); PHASE8(4, kt2, 0);
          PHASE8(5, kt2, 0); PHASE8(6, kt2, 0); PHASE8(7, kt2, 0); PHASE8(8, kt2, 0); }
    }

    // epilogue: C/D layout col = lane&15, row = (lane>>4)*4 + r
    const int er0 = m0 + wr * 128 + (l >> 4) * 4;
    const int ec0 = n0 + wc * WN + lm;
#pragma unroll
    for (int mi = 0; mi < 8; ++mi) {
#pragma unroll
        for (int nj = 0; nj < NJ; ++nj) {
#pragma unroll
            for (int r = 0; r < 4; ++r) {
                const int row = er0 + mi * 16 + r;
                const int col = ec0 + nj * 16;
                if constexpr (MODE == 2) {
                    const float v = (acc[mi][nj][r] + bias[biasRow ? row : col]) * scale;
                    ((ushort*)Cc)[(size_t)row * ldc_ + col] = f2bf(v);
                } else {
                    ((_Float16*)Cc)[(size_t)row * ldc_ + col] = (_Float16)acc[mi][nj][r];
                }
            }
        }
    }
#undef MPHASE
#undef PHASE8
#undef STAGE_H
#undef ROFFX
}

// ---------------------------------------------------------------------------
// Row softmax: S (fp16) -> P (bf16) in-place, fp32 math.
// Round-14: grid-stride, 2 rows per block (grid 2048). Trailing barrier
// protects redm/reds reuse across row iterations.
// ---------------------------------------------------------------------------
__global__ __launch_bounds__(256) void softmax_rows(void* __restrict__ Sbase) {
    const int tid = threadIdx.x;
    const int w = tid >> 6, l = tid & 63;
    __shared__ float redm[4], reds[4];

    for (int row = blockIdx.x; row < SEQ; row += 2048) {
        const _Float16* srow = (const _Float16*)Sbase + (size_t)row * SEQ;

        float f[16];
#pragma unroll
        for (int j = 0; j < 2; ++j) {
            h16x8 v = *(const h16x8*)(srow + (size_t)(tid + j * 256) * 8);
#pragma unroll
            for (int e = 0; e < 8; ++e) f[j * 8 + e] = (float)v[e];
        }

        float m = f[0];
#pragma unroll
        for (int i = 1; i < 16; ++i) m = fmaxf(m, f[i]);
#pragma unroll
        for (int off = 32; off > 0; off >>= 1) m = fmaxf(m, __shfl_xor(m, off));

        if (l == 0) redm[w] = m;
        __syncthreads();
        m = fmaxf(fmaxf(redm[0], redm[1]), fmaxf(redm[2], redm[3]));

        float s = 0.f;
#pragma unroll
        for (int i = 0; i < 16; ++i) { f[i] = __expf(f[i] - m); s += f[i]; }
#pragma unroll
        for (int off = 32; off > 0; off >>= 1) s += __shfl_xor(s, off);
        if (l == 0) reds[w] = s;
        __syncthreads();
        s = (reds[0] + reds[1]) + (reds[2] + reds[3]);
        const float inv = 1.0f / s;

        ushort* prow = (ushort*)Sbase + (size_t)row * SEQ;
#pragma unroll
        for (int j = 0; j < 2; ++j) {
            s16x8 o;
#pragma unroll
            for (int e = 0; e < 8; ++e) o[e] = (short)f2bf(f[j * 8 + e] * inv);
            *(s16x8*)(prow + (size_t)(tid + j * 256) * 8) = o;
        }
        __syncthreads();   // protect redm/reds before next row iteration
    }
}

// ---------------------------------------------------------------------------
// split-K reduce: out[j] = p0[j] + p1[j]  (f16 partials -> f32)
// ---------------------------------------------------------------------------
__global__ __launch_bounds__(256)
void reduce2(const _Float16* __restrict__ p0, const _Float16* __restrict__ p1,
             float* __restrict__ out)
{
    const size_t i = (size_t)(blockIdx.x * 256 + threadIdx.x) * 8;
    h16x8 a = *(const h16x8*)(p0 + i);
    h16x8 b = *(const h16x8*)(p1 + i);
    float4 o0, o1;
    o0.x = (float)a[0] + (float)b[0]; o0.y = (float)a[1] + (float)b[1];
    o0.z = (float)a[2] + (float)b[2]; o0.w = (float)a[3] + (float)b[3];
    o1.x = (float)a[4] + (float)b[4]; o1.y = (float)a[5] + (float)b[5];
    o1.z = (float)a[6] + (float)b[6]; o1.w = (float)a[7] + (float)b[7];
    *(float4*)(out + i) = o0;
    *(float4*)(out + i + 4) = o1;
}

// ---------------------------------------------------------------------------
extern "C" void kernel_launch(void* const* d_in, const int* in_sizes, int n_in,
                              void* d_out, int out_size, void* d_ws, size_t ws_size,
                              hipStream_t stream)
{
    const float* x  = (const float*)d_in[0];
    const float* wq = (const float*)d_in[1];
    const float* bq = (const float*)d_in[2];
    const float* wk = (const float*)d_in[3];
    const float* bk = (const float*)d_in[4];
    const float* wv = (const float*)d_in[5];
    const float* bv = (const float*)d_in[6];

    char* ws = (char*)d_ws;
    const size_t MB = 1024 * 1024;
    // layout (56 MB):
    //  [0,8)   Qb bf16 [4096][1024] -> PV partial 0 (f16) after scores
    //  [8,16)  Kb bf16              -> PV partial 1 (f16) after scores
    //  [16,24) Vt bf16 [1024][4096]
    //  [24,56) S  f16  [4096][4096] -> P bf16 in-place
    //  [24,32) xb bf16 (dead before S written); [32,38) weights bf16 (dead)
    ushort*   Qb  = (ushort*)(ws);
    ushort*   Kb  = (ushort*)(ws + 8 * MB);
    ushort*   Vt  = (ushort*)(ws + 16 * MB);
    void*     Sm  = (void*)(ws + 24 * MB);
    ushort*   P   = (ushort*)(ws + 24 * MB);
    ushort*   xb  = (ushort*)(ws + 24 * MB);
    ushort*   wqb = (ushort*)(ws + 32 * MB);
    ushort*   wkb = (ushort*)(ws + 34 * MB);
    ushort*   wvb = (ushort*)(ws + 36 * MB);
    _Float16* Pp  = (_Float16*)(ws);            // partials: ks * 4M f16 elems

    // 1) converts (one launch)
    cvt_all<<<dim3(7168), dim3(256), 0, stream>>>(x, wq, wk, wv, xb, wqb, wkb, wvb);

    // 2) fused QKV: Q=(x wq^T + bq)/32, K=x wk^T + bk, Vt=wv x^T + bv[row]
    gemm256p<2><<<dim3(192), dim3(512), 0, stream>>>(
        xb, wqb, Qb, xb, wkb, Kb, wvb, xb, Vt, bq, bk, bv);

    // 3) scores: S = Qs @ K^T (f16), 8-phase 256^2
    gemm256p<0><<<dim3(256), dim3(512), 0, stream>>>(
        Qb, Kb, Sm, nullptr, nullptr, nullptr, nullptr, nullptr, nullptr,
        nullptr, nullptr, nullptr);

    // 4) softmax rows (in-place f16 -> bf16), grid-stride 2 rows/block
    softmax_rows<<<dim3(2048), dim3(256), 0, stream>>>(Sm);

    // 5) PV split-K=2, merged-phase 256x128 -> f16 partials in [0,16) MB
    gemm256p<1><<<dim3(256), dim3(512), 0, stream>>>(
        P, Vt, Pp, nullptr, nullptr, nullptr, nullptr, nullptr, nullptr,
        nullptr, nullptr, nullptr);

    // 6) reduce partials -> f32 d_out
    reduce2<<<dim3(2048), dim3(256), 0, stream>>>(Pp, Pp + (size_t)4096 * 1024,
                                                  (float*)d_out);
}